// Round 1
// baseline (2530.018 us; speedup 1.0000x reference)
//
#include <hip/hip_runtime.h>

typedef __bf16 bf16x8 __attribute__((ext_vector_type(8)));
typedef float f32x4 __attribute__((ext_vector_type(4)));
typedef unsigned short u16;
typedef unsigned int u32;

#define T_ 64
#define B_ 1024
#define E_ 1024
#define H_ 1024
#define G4_ 4096

__device__ inline u16 f2bf(float f) {
  u32 u = __float_as_uint(f);
  u32 r = (u + 0x7fffu + ((u >> 16) & 1u)) >> 16;  // RNE
  return (u16)r;
}

__device__ inline uint2 cvt4(float4 v) {
  uint2 r;
  r.x = (u32)f2bf(v.x) | ((u32)f2bf(v.y) << 16);
  r.y = (u32)f2bf(v.z) | ((u32)f2bf(v.w) << 16);
  return r;
}

// ---------- prep: Wb=[W_ih|W_hh] bf16 [4096][2048], bcomb=b_ih+b_hh, hb=bf16(h0), c=c0
__global__ void prep_kernel(const float* __restrict__ W_ih, const float* __restrict__ W_hh,
                            const float* __restrict__ b_ih, const float* __restrict__ b_hh,
                            const float* __restrict__ h0, const float* __restrict__ c0,
                            u16* __restrict__ Wb, float* __restrict__ bcomb,
                            u16* __restrict__ hb, float* __restrict__ c) {
  int gid = blockIdx.x * 256 + threadIdx.x;   // 8192*256 threads, 4 elems each = 8,388,608
  {
    int base = gid << 2;
    int n = base >> 11;        // row in [0,4096)
    int k = base & 2047;       // col in [0,2048), 4-aligned so no boundary crossing
    float4 v = (k < 1024) ? *(const float4*)(W_ih + n * 1024 + k)
                          : *(const float4*)(W_hh + n * 1024 + (k - 1024));
    *(uint2*)(Wb + base) = cvt4(v);
  }
  if (gid < (B_ * H_ / 4)) {
    int base = gid << 2;
    *(float4*)(c + base) = *(const float4*)(c0 + base);
    *(uint2*)(hb + base) = cvt4(*(const float4*)(h0 + base));
  }
  if (gid < (G4_ / 4)) {
    int base = gid << 2;
    float4 a = *(const float4*)(b_ih + base);
    float4 b = *(const float4*)(b_hh + base);
    *(float4*)(bcomb + base) = make_float4(a.x + b.x, a.y + b.y, a.z + b.z, a.w + b.w);
  }
}

// ---------- per-step embedding gather + bf16 cast: XE[b][e] = bf16(emb[x[b,t]][e])
__global__ void gather_kernel(const int* __restrict__ x, const float* __restrict__ emb,
                              u16* __restrict__ XE, int t) {
  int b = blockIdx.x;
  int row = x[b * T_ + t];
  int e = threadIdx.x << 2;   // 256 threads * 4 = 1024
  float4 v = *(const float4*)(emb + (size_t)row * E_ + e);
  *(uint2*)(XE + b * E_ + e) = cvt4(v);
}

// ---------- gates GEMM: G[z][b][n] = sum_k A_z[b][k] * Wb[n][z*1024+k]
// A_0 = XE (x-projection half), A_1 = hb (recurrent half). Split-K=2 for occupancy.
// 128x128 block tile, 4 waves of 64x64, mfma_f32_16x16x32_bf16, XOR-swizzled LDS.
__global__ void __launch_bounds__(256, 2) gemm_kernel(
    const u16* __restrict__ XE, const u16* __restrict__ hb,
    const u16* __restrict__ Wb, float* __restrict__ G) {
  __shared__ u16 lsA[128 * 64];   // 16 KB, swizzled row-major [128][64] bf16
  __shared__ u16 lsB[128 * 64];   // 16 KB
  const int tid = threadIdx.x;
  const int lane = tid & 63;
  const int wave = tid >> 6;        // 0..3
  const int wm = wave >> 1;         // 0..1
  const int wn = wave & 1;          // 0..1
  const int n0 = blockIdx.x * 128;  // N-tile (x fastest -> XCD groups share B-panels)
  const int m0 = blockIdx.y * 128;  // M-tile
  const int z = blockIdx.z;         // K-split

  const u16* Asrc = z ? hb : XE;              // [1024][1024] bf16
  const u16* Bsrc = Wb + z * 1024;            // rows [4096], stride 2048
  float* Gout = G + (size_t)z * B_ * G4_;

  f32x4 acc[4][4] = {};

  // staging map: linear LDS byte beta <- pre-swizzled global column (rule #21)
  int srow[4], skA[4];
#pragma unroll
  for (int q = 0; q < 4; ++q) {
    int beta = (q * 256 + tid) * 16;
    int row = beta >> 7;                          // 128 B per row
    int kb = (beta ^ ((row & 7) << 4)) & 127;     // swizzled byte-in-row
    srow[q] = row;
    skA[q] = kb >> 1;                             // bf16 element index
  }

  for (int kt = 0; kt < 16; ++kt) {               // K-half = 1024 = 16 * 64
    int k0 = kt * 64;
#pragma unroll
    for (int q = 0; q < 4; ++q) {
      int beta = (q * 256 + tid) * 16;
      uint4 va = *(const uint4*)(Asrc + (m0 + srow[q]) * 1024 + k0 + skA[q]);
      uint4 vb = *(const uint4*)(Bsrc + (n0 + srow[q]) * 2048 + k0 + skA[q]);
      *(uint4*)((char*)lsA + beta) = va;
      *(uint4*)((char*)lsB + beta) = vb;
    }
    __syncthreads();
#pragma unroll
    for (int kk = 0; kk < 2; ++kk) {
      const int koff2 = (kk * 32 + ((lane >> 4) << 3)) << 1;  // byte offset of k in row
      bf16x8 af[4], bfr[4];
#pragma unroll
      for (int mi = 0; mi < 4; ++mi) {
        int row = wm * 64 + mi * 16 + (lane & 15);
        int bofs = ((row << 7) | koff2) ^ ((row & 7) << 4);
        af[mi] = *(const bf16x8*)((const char*)lsA + bofs);
      }
#pragma unroll
      for (int ni = 0; ni < 4; ++ni) {
        int row = wn * 64 + ni * 16 + (lane & 15);
        int bofs = ((row << 7) | koff2) ^ ((row & 7) << 4);
        bfr[ni] = *(const bf16x8*)((const char*)lsB + bofs);
      }
#pragma unroll
      for (int mi = 0; mi < 4; ++mi)
#pragma unroll
        for (int ni = 0; ni < 4; ++ni)
          acc[mi][ni] = __builtin_amdgcn_mfma_f32_16x16x32_bf16(af[mi], bfr[ni], acc[mi][ni], 0, 0, 0);
    }
    __syncthreads();
  }

  // C/D layout: col = lane&15, row = (lane>>4)*4 + reg  [m89/m91]
  const int rbase = (lane >> 4) << 2;
  const int cbase = lane & 15;
#pragma unroll
  for (int mi = 0; mi < 4; ++mi) {
    int grow = m0 + wm * 64 + mi * 16 + rbase;
#pragma unroll
    for (int ni = 0; ni < 4; ++ni) {
      int gcol = n0 + wn * 64 + ni * 16 + cbase;
#pragma unroll
      for (int r = 0; r < 4; ++r)
        Gout[(size_t)(grow + r) * G4_ + gcol] = acc[mi][ni][r];
    }
  }
}

// ---------- LSTM cell pointwise + per-step 2-class log-softmax head on c2
__global__ void cell_kernel(const float* __restrict__ G, const float* __restrict__ bcomb,
                            const float* __restrict__ Wout, const float* __restrict__ bout,
                            float* __restrict__ c, u16* __restrict__ hb,
                            float* __restrict__ outp) {
  int b = blockIdx.x, tid = threadIdx.x;
  const float* g0 = G + (size_t)b * G4_;
  const float* g1 = g0 + (size_t)B_ * G4_;
  float a0 = 0.f, a1 = 0.f;
#pragma unroll
  for (int q = 0; q < 4; ++q) {
    int j = q * 256 + tid;
    float gi = g0[j]        + g1[j]        + bcomb[j];
    float gf = g0[1024 + j] + g1[1024 + j] + bcomb[1024 + j];
    float gg = g0[2048 + j] + g1[2048 + j] + bcomb[2048 + j];
    float go = g0[3072 + j] + g1[3072 + j] + bcomb[3072 + j];
    float si = 1.f / (1.f + expf(-gi));
    float sf = 1.f / (1.f + expf(-gf));
    float so = 1.f / (1.f + expf(-go));
    float c2 = sf * c[b * H_ + j] + si * tanhf(gg);
    float h2 = so * tanhf(c2);
    c[b * H_ + j] = c2;
    hb[b * H_ + j] = f2bf(h2);
    a0 += c2 * Wout[j];
    a1 += c2 * Wout[1024 + j];
  }
#pragma unroll
  for (int off = 32; off; off >>= 1) {
    a0 += __shfl_down(a0, off);
    a1 += __shfl_down(a1, off);
  }
  __shared__ float red[8];
  if ((tid & 63) == 0) { red[tid >> 6] = a0; red[4 + (tid >> 6)] = a1; }
  __syncthreads();
  if (tid == 0) {
    float l0 = red[0] + red[1] + red[2] + red[3] + bout[0];
    float l1 = red[4] + red[5] + red[6] + red[7] + bout[1];
    float m = fmaxf(l0, l1);
    float ls = m + logf(expf(l0 - m) + expf(l1 - m));
    outp[b * 2 + 0] = l0 - ls;
    outp[b * 2 + 1] = l1 - ls;
  }
}

// ---------- final linear head on cT (no log-softmax)
__global__ void final_kernel(const float* __restrict__ c, const float* __restrict__ Wout,
                             const float* __restrict__ bout, float* __restrict__ outp) {
  int b = blockIdx.x, tid = threadIdx.x;
  float a0 = 0.f, a1 = 0.f;
#pragma unroll
  for (int q = 0; q < 4; ++q) {
    int j = q * 256 + tid;
    float cv = c[b * H_ + j];
    a0 += cv * Wout[j];
    a1 += cv * Wout[1024 + j];
  }
#pragma unroll
  for (int off = 32; off; off >>= 1) {
    a0 += __shfl_down(a0, off);
    a1 += __shfl_down(a1, off);
  }
  __shared__ float red[8];
  if ((tid & 63) == 0) { red[tid >> 6] = a0; red[4 + (tid >> 6)] = a1; }
  __syncthreads();
  if (tid == 0) {
    outp[b * 2 + 0] = red[0] + red[1] + red[2] + red[3] + bout[0];
    outp[b * 2 + 1] = red[4] + red[5] + red[6] + red[7] + bout[1];
  }
}

extern "C" void kernel_launch(void* const* d_in, const int* in_sizes, int n_in,
                              void* d_out, int out_size, void* d_ws, size_t ws_size,
                              hipStream_t stream) {
  const int* x      = (const int*)d_in[0];
  const float* emb  = (const float*)d_in[1];
  const float* W_ih = (const float*)d_in[2];
  const float* W_hh = (const float*)d_in[3];
  const float* b_ih = (const float*)d_in[4];
  const float* b_hh = (const float*)d_in[5];
  const float* W_out = (const float*)d_in[6];
  const float* b_out = (const float*)d_in[7];
  const float* h0   = (const float*)d_in[8];
  const float* c0   = (const float*)d_in[9];
  float* out = (float*)d_out;

  // workspace layout (~56 MB)
  char* w = (char*)d_ws;
  u16* Wb   = (u16*)w;   w += (size_t)4096 * 2048 * 2;          // 16 MB
  float* G  = (float*)w; w += (size_t)2 * 1024 * 4096 * 4;      // 32 MB (split-K partials)
  float* c  = (float*)w; w += (size_t)1024 * 1024 * 4;          // 4 MB
  u16* hb   = (u16*)w;   w += (size_t)1024 * 1024 * 2;          // 2 MB
  u16* XE   = (u16*)w;   w += (size_t)1024 * 1024 * 2;          // 2 MB
  float* bcomb = (float*)w; w += (size_t)4096 * 4;

  prep_kernel<<<8192, 256, 0, stream>>>(W_ih, W_hh, b_ih, b_hh, h0, c0, Wb, bcomb, hb, c);
  for (int t = 0; t < T_; ++t) {
    gather_kernel<<<1024, 256, 0, stream>>>(x, emb, XE, t);
    gemm_kernel<<<dim3(32, 8, 2), 256, 0, stream>>>(XE, hb, Wb, G);
    cell_kernel<<<1024, 256, 0, stream>>>(G, bcomb, W_out, b_out, c, hb,
                                          out + (size_t)t * B_ * 2);
  }
  final_kernel<<<1024, 256, 0, stream>>>(c, W_out, b_out, out + (size_t)T_ * B_ * 2);
}

// Round 2
// 2144.260 us; speedup vs baseline: 1.1799x; 1.1799x over previous
//
#include <hip/hip_runtime.h>

typedef __bf16 bf16x8 __attribute__((ext_vector_type(8)));
typedef float f32x4 __attribute__((ext_vector_type(4)));
typedef unsigned short u16;
typedef unsigned int u32;

#define T_ 64
#define B_ 1024
#define H_ 1024
#define G4_ 4096
#define HB_ (B_ * H_)

__device__ inline u16 f2bf(float f) {
  u32 u = __float_as_uint(f);
  u32 r = (u + 0x7fffu + ((u >> 16) & 1u)) >> 16;  // RNE
  return (u16)r;
}

__device__ inline uint2 cvt4(float4 v) {
  uint2 r;
  r.x = (u32)f2bf(v.x) | ((u32)f2bf(v.y) << 16);
  r.y = (u32)f2bf(v.z) | ((u32)f2bf(v.w) << 16);
  return r;
}

__device__ __forceinline__ void gload16(const void* g, void* l) {
  __builtin_amdgcn_global_load_lds(
      (const __attribute__((address_space(1))) unsigned int*)g,
      (__attribute__((address_space(3))) unsigned int*)l, 16, 0, 0);
}

// ---------- prep: WbP = gate-interleaved [W_ih | W_hh] bf16 [4096][2048],
// bcP = permuted b_ih+b_hh, hb0 = bf16(h0), c = c0.
// Permutation: n' = (j>>4)*64 + gate*16 + (j&15)  <=>  gate=(n'>>4)&3, j=((n'>>6)<<4)|(n'&15)
__global__ void prep_kernel(const float* __restrict__ W_ih, const float* __restrict__ W_hh,
                            const float* __restrict__ b_ih, const float* __restrict__ b_hh,
                            const float* __restrict__ h0, const float* __restrict__ c0,
                            u16* __restrict__ WbP, float* __restrict__ bcP,
                            u16* __restrict__ hb0, float* __restrict__ c) {
  int gid = blockIdx.x * 256 + threadIdx.x;  // 2,097,152 threads, 4 elems each
  {
    int base = gid << 2;
    int np = base >> 11;                         // permuted row
    int k = base & 2047;                         // col, 4-aligned
    int gate = (np >> 4) & 3;
    int j = ((np >> 6) << 4) | (np & 15);
    int srow = gate * 1024 + j;
    float4 v = (k < 1024) ? *(const float4*)(W_ih + (size_t)srow * 1024 + k)
                          : *(const float4*)(W_hh + (size_t)srow * 1024 + (k - 1024));
    *(uint2*)(WbP + base) = cvt4(v);
  }
  if (gid < (HB_ / 4)) {
    int base = gid << 2;
    *(float4*)(c + base) = *(const float4*)(c0 + base);
    *(uint2*)(hb0 + base) = cvt4(*(const float4*)(h0 + base));
  }
  if (gid < G4_) {
    int np = gid;
    int gate = (np >> 4) & 3;
    int j = ((np >> 6) << 4) | (np & 15);
    int srcn = gate * 1024 + j;
    bcP[np] = b_ih[srcn] + b_hh[srcn];
  }
}

// ---------- embedding gather + bf16 cast (step t)
__global__ void gather_kernel(const int* __restrict__ x, const float* __restrict__ emb,
                              u16* __restrict__ XE, int t) {
  int b = blockIdx.x;
  int row = x[b * T_ + t];
  int e = threadIdx.x << 2;
  float4 v = *(const float4*)(emb + (size_t)row * H_ + e);
  *(uint2*)(XE + (size_t)b * H_ + e) = cvt4(v);
}

// ---------- fused gates-GEMM + LSTM cell epilogue.
// A = [XE | hbR] [1024][2048] bf16, B = WbP [4096][2048] (gate-interleaved rows).
// BM=128, BN=64, 4 waves = (qm = M-half, kh = K-half). Wave tile 64x64, acc[4][4].
// LDS: lsA [128 rows][256B] (K-halves side by side), lsB [64][256B]; XOR swizzle
// byte ^= (row&7)<<4 applied via pre-swizzled global source + linear gl_lds dest.
__global__ void __launch_bounds__(256, 2) gemm_cell_kernel(
    const u16* __restrict__ XE, const u16* __restrict__ hbR,
    const u16* __restrict__ WbP, const float* __restrict__ bcP,
    float* __restrict__ c, u16* __restrict__ hbW) {
  __shared__ char smem[49152];  // 32KB lsA + 16KB lsB; 32KB overlay for acc exchange
  const int tid = threadIdx.x;
  const int lane = tid & 63;
  const int wave = tid >> 6;   // 0..3
  const int qm = wave >> 1;    // M-half 0/1
  const int kh = wave & 1;     // K-half 0/1
  const int n0 = blockIdx.x * 64;
  const int m0 = blockIdx.y * 128;

  // staging: LDS linear byte beta <- pre-swizzled source (rule #21 pattern)
  const u16* srcA[8];
  const u16* srcB[4];
  int betaA[8], betaB[4];
#pragma unroll
  for (int s = 0; s < 8; ++s) {
    int beta = (s * 256 + tid) * 16;               // 0..32K
    int row = beta >> 8;                           // 0..127
    int colu = (beta & 255) ^ ((row & 7) << 4);    // unswizzled col-byte
    int half = colu >> 7;                          // K-half
    int kl = (colu & 127) >> 1;                    // k-local element (8-aligned)
    srcA[s] = (half ? hbR : XE) + (size_t)(m0 + row) * 1024 + kl;
    betaA[s] = beta;
  }
#pragma unroll
  for (int s = 0; s < 4; ++s) {
    int beta = (s * 256 + tid) * 16;               // 0..16K
    int row = beta >> 8;                           // 0..63
    int colu = (beta & 255) ^ ((row & 7) << 4);
    int half = colu >> 7;
    int kl = (colu & 127) >> 1;
    srcB[s] = WbP + (size_t)(n0 + row) * 2048 + half * 1024 + kl;
    betaB[s] = 32768 + beta;
  }

  f32x4 acc[4][4] = {};
  const int kbase = kh << 7;            // this wave's K-half col-byte base
  const int rsel = lane & 15;
  const int ksel = (lane >> 4) << 4;    // 16-byte k offset within 128B half

  for (int kt = 0; kt < 16; ++kt) {
#pragma unroll
    for (int s = 0; s < 8; ++s) gload16(srcA[s], smem + betaA[s]);
#pragma unroll
    for (int s = 0; s < 4; ++s) gload16(srcB[s], smem + betaB[s]);
#pragma unroll
    for (int s = 0; s < 8; ++s) srcA[s] += 64;
#pragma unroll
    for (int s = 0; s < 4; ++s) srcB[s] += 64;
    __syncthreads();
#pragma unroll
    for (int kk = 0; kk < 2; ++kk) {
      const int colb = kbase + kk * 64 + ksel;
      bf16x8 af[4], bfr[4];
#pragma unroll
      for (int mi = 0; mi < 4; ++mi) {
        int row = qm * 64 + mi * 16 + rsel;
        af[mi] = *(const bf16x8*)(smem + row * 256 + (colb ^ ((row & 7) << 4)));
      }
#pragma unroll
      for (int ni = 0; ni < 4; ++ni) {
        int row = ni * 16 + rsel;
        bfr[ni] = *(const bf16x8*)(smem + 32768 + row * 256 + (colb ^ ((row & 7) << 4)));
      }
#pragma unroll
      for (int mi = 0; mi < 4; ++mi)
#pragma unroll
        for (int ni = 0; ni < 4; ++ni)
          acc[mi][ni] = __builtin_amdgcn_mfma_f32_16x16x32_bf16(af[mi], bfr[ni], acc[mi][ni], 0, 0, 0);
    }
    __syncthreads();
  }

  // ---- combine K-halves + LSTM cell. C/D layout: col=lane&15, row=(lane>>4)*4+reg.
  float* lsX = (float*)smem;  // [2 qm][64 rows][64 cols] f32 = 32KB
  const int rbase = (lane >> 4) << 2;
  const int cbase = lane & 15;
  if (kh == 1) {
#pragma unroll
    for (int mi = 0; mi < 4; ++mi)
#pragma unroll
      for (int ni = 0; ni < 4; ++ni)
#pragma unroll
        for (int r = 0; r < 4; ++r)
          lsX[qm * 4096 + (mi * 16 + rbase + r) * 64 + ni * 16 + cbase] = acc[mi][ni][r];
  }
  __syncthreads();
  if (kh == 0) {
    const float bias0 = bcP[n0 + cbase];
    const float bias1 = bcP[n0 + 16 + cbase];
    const float bias2 = bcP[n0 + 32 + cbase];
    const float bias3 = bcP[n0 + 48 + cbase];
    const int j = blockIdx.x * 16 + cbase;  // hidden index owned by this thread
#pragma unroll
    for (int mi = 0; mi < 4; ++mi) {
#pragma unroll
      for (int r = 0; r < 4; ++r) {
        int rl = mi * 16 + rbase + r;
        int b = m0 + qm * 64 + rl;
        int xb = qm * 4096 + rl * 64 + cbase;
        float gi = acc[mi][0][r] + lsX[xb] + bias0;
        float gf = acc[mi][1][r] + lsX[xb + 16] + bias1;
        float gg = acc[mi][2][r] + lsX[xb + 32] + bias2;
        float go = acc[mi][3][r] + lsX[xb + 48] + bias3;
        float si = 1.f / (1.f + expf(-gi));
        float sf = 1.f / (1.f + expf(-gf));
        float so = 1.f / (1.f + expf(-go));
        size_t idx = (size_t)b * H_ + j;
        float c2 = sf * c[idx] + si * tanhf(gg);
        float h2 = so * tanhf(c2);
        c[idx] = c2;
        hbW[idx] = f2bf(h2);
      }
    }
  }
}

// ---------- head(t) on c (log-softmax over 2 classes) + gather(t1) for next step
__global__ void head_gather_kernel(const float* __restrict__ c, const float* __restrict__ Wout,
                                   const float* __restrict__ bout, float* __restrict__ outp,
                                   const int* __restrict__ x, const float* __restrict__ emb,
                                   u16* __restrict__ XE, int t1) {
  int b = blockIdx.x, tid = threadIdx.x;
  if (t1 < T_) {  // gather for next step (independent of head)
    int row = x[b * T_ + t1];
    int e = tid << 2;
    float4 v = *(const float4*)(emb + (size_t)row * H_ + e);
    *(uint2*)(XE + (size_t)b * H_ + e) = cvt4(v);
  }
  float a0 = 0.f, a1 = 0.f;
#pragma unroll
  for (int q = 0; q < 4; ++q) {
    int jj = q * 256 + tid;
    float cv = c[(size_t)b * H_ + jj];
    a0 += cv * Wout[jj];
    a1 += cv * Wout[1024 + jj];
  }
#pragma unroll
  for (int off = 32; off; off >>= 1) {
    a0 += __shfl_down(a0, off);
    a1 += __shfl_down(a1, off);
  }
  __shared__ float red[8];
  if ((tid & 63) == 0) { red[tid >> 6] = a0; red[4 + (tid >> 6)] = a1; }
  __syncthreads();
  if (tid == 0) {
    float l0 = red[0] + red[1] + red[2] + red[3] + bout[0];
    float l1 = red[4] + red[5] + red[6] + red[7] + bout[1];
    float m = fmaxf(l0, l1);
    float ls = m + logf(expf(l0 - m) + expf(l1 - m));
    outp[b * 2 + 0] = l0 - ls;
    outp[b * 2 + 1] = l1 - ls;
  }
}

// ---------- final linear head on cT (no softmax)
__global__ void final_kernel(const float* __restrict__ c, const float* __restrict__ Wout,
                             const float* __restrict__ bout, float* __restrict__ outp) {
  int b = blockIdx.x, tid = threadIdx.x;
  float a0 = 0.f, a1 = 0.f;
#pragma unroll
  for (int q = 0; q < 4; ++q) {
    int jj = q * 256 + tid;
    float cv = c[(size_t)b * H_ + jj];
    a0 += cv * Wout[jj];
    a1 += cv * Wout[1024 + jj];
  }
#pragma unroll
  for (int off = 32; off; off >>= 1) {
    a0 += __shfl_down(a0, off);
    a1 += __shfl_down(a1, off);
  }
  __shared__ float red[8];
  if ((tid & 63) == 0) { red[tid >> 6] = a0; red[4 + (tid >> 6)] = a1; }
  __syncthreads();
  if (tid == 0) {
    outp[b * 2 + 0] = red[0] + red[1] + red[2] + red[3] + bout[0];
    outp[b * 2 + 1] = red[4] + red[5] + red[6] + red[7] + bout[1];
  }
}

extern "C" void kernel_launch(void* const* d_in, const int* in_sizes, int n_in,
                              void* d_out, int out_size, void* d_ws, size_t ws_size,
                              hipStream_t stream) {
  const int* x      = (const int*)d_in[0];
  const float* emb  = (const float*)d_in[1];
  const float* W_ih = (const float*)d_in[2];
  const float* W_hh = (const float*)d_in[3];
  const float* b_ih = (const float*)d_in[4];
  const float* b_hh = (const float*)d_in[5];
  const float* W_out = (const float*)d_in[6];
  const float* b_out = (const float*)d_in[7];
  const float* h0   = (const float*)d_in[8];
  const float* c0   = (const float*)d_in[9];
  float* out = (float*)d_out;

  // workspace (~26 MB)
  char* w = (char*)d_ws;
  u16* WbP  = (u16*)w;   w += (size_t)G4_ * 2048 * 2;     // 16 MB
  float* c  = (float*)w; w += (size_t)HB_ * 4;            // 4 MB
  u16* hb   = (u16*)w;   w += (size_t)2 * HB_ * 2;        // 4 MB (double buffer)
  u16* XE   = (u16*)w;   w += (size_t)HB_ * 2;            // 2 MB
  float* bcP = (float*)w; w += (size_t)G4_ * 4;

  prep_kernel<<<8192, 256, 0, stream>>>(W_ih, W_hh, b_ih, b_hh, h0, c0, WbP, bcP, hb, c);
  gather_kernel<<<1024, 256, 0, stream>>>(x, emb, XE, 0);
  for (int t = 0; t < T_; ++t) {
    u16* hbR = hb + (size_t)(t & 1) * HB_;
    u16* hbW = hb + (size_t)((t + 1) & 1) * HB_;
    gemm_cell_kernel<<<dim3(64, 8), 256, 0, stream>>>(XE, hbR, WbP, bcP, c, hbW);
    head_gather_kernel<<<1024, 256, 0, stream>>>(c, W_out, b_out, out + (size_t)t * B_ * 2,
                                                 x, emb, XE, t + 1);
  }
  final_kernel<<<1024, 256, 0, stream>>>(c, W_out, b_out, out + (size_t)T_ * B_ * 2);
}